// Round 17
// baseline (62.803 us; speedup 1.0000x reference)
//
#include <hip/hip_runtime.h>
#include <hip/hip_bf16.h>
#include <stdint.h>

typedef float    f32x4 __attribute__((ext_vector_type(4)));
typedef _Float16 f16x4 __attribute__((ext_vector_type(4)));
typedef _Float16 f16x8 __attribute__((ext_vector_type(8)));

#define NSTEPS 15

// ---------------------------------------------------------------------------
// Fused prep kernel (byte-identical to R13)
// ---------------------------------------------------------------------------
__global__ __launch_bounds__(256) void prep_kernel(
    const float* __restrict__ embed, const float* __restrict__ W1,
    const float* __restrict__ W2,
    _Float16* __restrict__ Ap, _Float16* __restrict__ Btp,
    _Float16* __restrict__ W2T)
{
  __shared__ _Float16 sh[2][64][72];
  const int b = blockIdx.x;
  const int t = threadIdx.x;

  if (b < 1024) {                       // ---- split_e (Dekker two-way split)
    const int i  = b * 256 + t;
    const int m  = i >> 7;
    const int k4 = (i & 127) * 4;
    f32x4 v = *(const f32x4*)&embed[(size_t)m * 512 + k4];
    f16x4 h0, h1;
#pragma unroll
    for (int j = 0; j < 4; ++j) {
      h0[j] = (_Float16)v[j];
      h1[j] = (_Float16)(v[j] - (float)h0[j]);
    }
    _Float16* r = Ap + (size_t)m * 1024 + k4;
    *(f16x4*)(r)       = h0;
    *(f16x4*)(r + 512) = h1;
  } else if (b < 1152) {                // ---- w1t_split (transpose + 64x + split)
    const int idx = b - 1024;
    const int n0 = (idx & 7) * 64;
    const int k0 = ((idx >> 3) & 7) * 64;
    const int z  = idx >> 6;
    const int kk = t >> 4;
    const int n4 = (t & 15) * 4;
#pragma unroll
    for (int i = 0; i < 4; ++i) {
      f32x4 v = *(const f32x4*)&W1[(size_t)(z * 512 + k0 + kk + i * 16) * 512 + n0 + n4];
#pragma unroll
      for (int j = 0; j < 4; ++j) {
        float s = v[j] * 64.0f;         // exact pow2 scale
        _Float16 hi = (_Float16)s;
        sh[0][n4 + j][kk + i * 16] = hi;
        sh[1][n4 + j][kk + i * 16] = (_Float16)(s - (float)hi);
      }
    }
    __syncthreads();
#pragma unroll
    for (int i = 0; i < 2; ++i) {
      const int nn = (t >> 3) + i * 32;
      const int k8 = (t & 7) * 8;
      _Float16* r = Btp + (size_t)(z * 512 + n0 + nn) * 1024 + k0 + k8;
      *(uint4*)(r)       = *(const uint4*)&sh[0][nn][k8];
      *(uint4*)(r + 512) = *(const uint4*)&sh[1][nn][k8];
    }
  } else {                              // ---- w2t (transpose + f16 convert)
    const int idx = b - 1152;
    const int n0 = (idx & 31) * 64;
    const int k0 = (idx >> 5) * 64;
    const int kk = t >> 4;
    const int n4 = (t & 15) * 4;
#pragma unroll
    for (int i = 0; i < 4; ++i) {
      f32x4 v = *(const f32x4*)&W2[(size_t)(k0 + kk + i * 16) * 2048 + n0 + n4];
#pragma unroll
      for (int j = 0; j < 4; ++j) sh[0][n4 + j][kk + i * 16] = (_Float16)v[j];
    }
    __syncthreads();
#pragma unroll
    for (int i = 0; i < 2; ++i) {
      const int nn = (t >> 3) + i * 32;
      const int k8 = (t & 7) * 8;
      *(uint4*)&W2T[(size_t)(n0 + nn) * 512 + k0 + k8] = *(const uint4*)&sh[0][nn][k8];
    }
  }
}

// ---------------------------------------------------------------------------
__device__ __forceinline__ void gld_lds16(const void* g, void* l) {
  __builtin_amdgcn_global_load_lds(
      (const __attribute__((address_space(1))) uint32_t*)g,
      (__attribute__((address_space(3))) uint32_t*)l, 16, 0, 0);
}

// ---------------------------------------------------------------------------
// gemm1 (byte-identical to R11/R13)
// ---------------------------------------------------------------------------
__device__ __forceinline__ void g1_stage(
    const _Float16* __restrict__ Ap, const _Float16* __restrict__ Btp,
    char* lds, int m0, int n0, int wave, int lane, int tile)
{
  const int vk0  = tile * 64;
  const int acol = (vk0 < 1024) ? vk0 : vk0 - 1024;
  const int bcol = (vk0 < 1024) ? (vk0 & 511) : vk0 - 512;
  char* lb = lds + (tile % 3) * 16384;
#pragma unroll
  for (int i = 0; i < 2; ++i) {      // A: 8 x 1KB chunks, 2 per wave
    const int ob  = (wave * 2 + i) * 1024;
    const int o   = ob + lane * 16;
    const int row = o >> 7;
    const int c   = ((o >> 4) & 7) ^ (row & 7);
    gld_lds16(Ap + ((size_t)(m0 + row) * 1024 + acol + c * 8), lb + ob);
  }
#pragma unroll
  for (int i = 0; i < 2; ++i) {      // B: 8 x 1KB chunks, 2 per wave
    const int ob  = (wave * 2 + i) * 1024;
    const int o   = ob + lane * 16;
    const int row = o >> 7;
    const int c   = ((o >> 4) & 7) ^ (row & 7);
    gld_lds16(Btp + ((size_t)(n0 + row) * 1024 + bcol + c * 8), lb + 8192 + ob);
  }
}

__global__ __launch_bounds__(256) void gemm1_kernel(
    const _Float16* __restrict__ Ap,   // [2048][1024]
    const _Float16* __restrict__ Btp,  // [1024][1024]
    float* __restrict__ T)             // [2048][1024]
{
  __shared__ __align__(16) char lds[3 * 16384];   // 48 KB ring

  const int t    = threadIdx.x;
  const int lane = t & 63;
  const int wave = t >> 6;
  const int wm   = wave >> 1;
  const int wn   = wave & 1;

  int bid = blockIdx.x;
  bid = (bid & 7) * 64 + (bid >> 3);   // XCD swizzle (512 % 8 == 0)
  const int m0 = (bid >> 4) * 64;      // 32 m-tiles
  const int n0 = (bid & 15) * 64;      // 16 n-tiles

  f32x4 acc[2][2] = {};

  g1_stage(Ap, Btp, lds, m0, n0, wave, lane, 0);
  g1_stage(Ap, Btp, lds, m0, n0, wave, lane, 1);
  asm volatile("s_waitcnt vmcnt(4)" ::: "memory");
  __builtin_amdgcn_s_barrier();

  for (int kt = 0; kt < 24; ++kt) {
    const char* lb = lds + (kt % 3) * 16384;
    char* AsB = (char*)lb;
    char* BsB = (char*)lb + 8192;
    const bool pf = (kt + 2 < 24);

    f16x8 af[2][2], bf[2][2];
#pragma unroll
    for (int kk = 0; kk < 2; ++kk) {
      const int lc = (lane >> 4) + kk * 4;
#pragma unroll
      for (int mi = 0; mi < 2; ++mi) {
        const int row = wm * 32 + mi * 16 + (lane & 15);
        af[mi][kk] = *(const f16x8*)(AsB + row * 128 + ((lc ^ (row & 7)) << 4));
      }
#pragma unroll
      for (int ni = 0; ni < 2; ++ni) {
        const int row = wn * 32 + ni * 16 + (lane & 15);
        bf[ni][kk] = *(const f16x8*)(BsB + row * 128 + ((lc ^ (row & 7)) << 4));
      }
    }
    if (pf) g1_stage(Ap, Btp, lds, m0, n0, wave, lane, kt + 2);

    __builtin_amdgcn_s_setprio(1);
#pragma unroll
    for (int kk = 0; kk < 2; ++kk)
#pragma unroll
      for (int mi = 0; mi < 2; ++mi)
#pragma unroll
        for (int ni = 0; ni < 2; ++ni)
          acc[mi][ni] = __builtin_amdgcn_mfma_f32_16x16x32_f16(
              af[mi][kk], bf[ni][kk], acc[mi][ni], 0, 0, 0);
    __builtin_amdgcn_s_setprio(0);

    if (pf) asm volatile("s_waitcnt vmcnt(4)" ::: "memory");
    else    asm volatile("s_waitcnt vmcnt(0)" ::: "memory");
    __builtin_amdgcn_s_barrier();
  }

#pragma unroll
  for (int mi = 0; mi < 2; ++mi) {
    const int r0 = m0 + wm * 32 + mi * 16 + ((lane >> 4) << 2);
#pragma unroll
    for (int ni = 0; ni < 2; ++ni) {
      const int cc = n0 + wn * 32 + ni * 16 + (lane & 15);
#pragma unroll
      for (int q = 0; q < 4; ++q)
        T[(size_t)(r0 + q) * 1024 + cc] = acc[mi][ni][q] * 0.015625f;
    }
  }
}

// ---------------------------------------------------------------------------
// recur (byte-identical to R13)
// ---------------------------------------------------------------------------
__global__ __launch_bounds__(256) void recur_kernel(
    const int* __restrict__ x,        // [8192][2]
    const float* __restrict__ T,      // [2048][1024]
    const float* __restrict__ b1,     // [512]
    const float* __restrict__ beta1p, const float* __restrict__ thr1p,
    const float* __restrict__ beta2p,
    _Float16* __restrict__ S)         // [8192][512]
{
  const float beta1 = fminf(fmaxf(beta1p[0], 0.1f), 0.9f);
  const float thr1  = fmaxf(thr1p[0], 0.1f);
  const float beta2 = fminf(fmaxf(beta2p[0], 0.1f), 0.9f);

  const int t = threadIdx.x;
  const int b = blockIdx.x * 4 + (t >> 6);
  const int h = (t & 63) * 8;
  const int x0 = x[b * 2 + 0];
  const int x1 = x[b * 2 + 1];

  const float* p0 = &T[(size_t)x0 * 1024 + h];
  const float* p1 = &T[(size_t)x1 * 1024 + 512 + h];

  float cur[8];
#pragma unroll
  for (int half = 0; half < 2; ++half) {
    f32x4 a = *(const f32x4*)(p0 + half * 4);
    f32x4 c = *(const f32x4*)(p1 + half * 4);
    f32x4 e = *(const f32x4*)&b1[h + half * 4];
#pragma unroll
    for (int j = 0; j < 4; ++j)
      cur[half * 4 + j] = (a[j] + c[j]) + e[j];
  }

  float m[8] = {}, s[8] = {};
#pragma unroll
  for (int st = 0; st < NSTEPS; ++st) {
#pragma unroll
    for (int j = 0; j < 8; ++j) {
      // reset uses PREVIOUS mem; spike uses UPDATED mem (snntorch Leaky, subtract)
      float r = (m[j] > thr1) ? thr1 : 0.0f;
      m[j] = beta1 * m[j] + cur[j] - r;
      float sp = (m[j] > thr1) ? 1.0f : 0.0f;
      s[j] = beta2 * s[j] + sp;   // S = sum_t beta2^{15-t} spk_t
    }
  }

  __align__(16) _Float16 o[8];
#pragma unroll
  for (int j = 0; j < 8; ++j) o[j] = (_Float16)s[j];
  *(uint4*)&S[(size_t)b * 512 + h] = *(const uint4*)o;
}

// ---------------------------------------------------------------------------
// gemm2 v5: 256x256 tile, BK=32, 512 threads, 8 waves (2M x 4N, per-wave
// 128x64). 3-deep ring 3x32KB = 96KB -> 1 block/CU, grid 256 (all CUs).
// Issued read traffic: A 8MBx8 + B 2MBx32 = 128MB (was 192MB at 256x128).
// Counted vmcnt(4). Coalesced LDS-transpose epilogue + nt stores.
// Per-element K accumulation order unchanged (kt ascending) -> bitwise-same.
// ---------------------------------------------------------------------------
__device__ __forceinline__ void g2_stage(
    const _Float16* __restrict__ A, const _Float16* __restrict__ Bt,
    char* lds, int m0, int n0, int wave, int lane, int tile)
{
  const int k0 = tile * 32;
  char* lb = lds + (tile % 3) * 32768;
#pragma unroll
  for (int i = 0; i < 2; ++i) {      // A: 256 rows x 64B = 16 chunks, 2/wave
    const int ob  = i * 8192 + wave * 1024;
    const int o   = ob + lane * 16;
    const int row = o >> 6;
    const int c   = ((o >> 4) & 3) ^ ((row >> 1) & 3);
    gld_lds16(A + ((size_t)(m0 + row) * 512 + k0 + c * 8), lb + ob);
  }
#pragma unroll
  for (int i = 0; i < 2; ++i) {      // B: 256 rows x 64B = 16 chunks, 2/wave
    const int ob  = i * 8192 + wave * 1024;
    const int o   = ob + lane * 16;
    const int row = o >> 6;
    const int c   = ((o >> 4) & 3) ^ ((row >> 1) & 3);
    gld_lds16(Bt + ((size_t)(n0 + row) * 512 + k0 + c * 8), lb + 16384 + ob);
  }
}

__global__ __launch_bounds__(512, 2) void gemm2_pipe_kernel(
    const _Float16* __restrict__ A,    // S   [8192][512]
    const _Float16* __restrict__ Bt,   // W2T [2048][512]
    const float* __restrict__ b2,      // [2048]
    const float* __restrict__ beta2p,
    float* __restrict__ C)             // [8192][2048]
{
  __shared__ __align__(16) char lds[3 * 32768];   // 96 KB

  const int t    = threadIdx.x;
  const int lane = t & 63;
  const int wave = t >> 6;
  const int wm   = wave >> 2;   // 0..1
  const int wn   = wave & 3;    // 0..3

  // m-stripe grouping by bid&7 (XCD under round-robin; harmless otherwise)
  const int bid = blockIdx.x;          // 0..255
  const int xcd = bid & 7;
  const int j   = bid >> 3;            // 0..31
  const int m0  = (xcd * 4 + (j >> 3)) * 256;   // 32 m-groups
  const int n0  = (j & 7) * 256;                //  8 n-groups

  f32x4 acc[8][4] = {};

  g2_stage(A, Bt, lds, m0, n0, wave, lane, 0);
  g2_stage(A, Bt, lds, m0, n0, wave, lane, 1);
  asm volatile("s_waitcnt vmcnt(4)" ::: "memory");
  __builtin_amdgcn_s_barrier();

  for (int kt = 0; kt < 16; ++kt) {
    const char* lb = lds + (kt % 3) * 32768;
    const bool pf = (kt + 2 < 16);

    const int lc = lane >> 4;
    f16x8 af[8], bf[4];
#pragma unroll
    for (int mi = 0; mi < 8; ++mi) {
      const int row = wm * 128 + mi * 16 + (lane & 15);
      af[mi] = *(const f16x8*)(lb + row * 64 + ((lc ^ ((row >> 1) & 3)) << 4));
    }
#pragma unroll
    for (int ni = 0; ni < 4; ++ni) {
      const int row = wn * 64 + ni * 16 + (lane & 15);
      bf[ni] = *(const f16x8*)(lb + 16384 + row * 64 + ((lc ^ ((row >> 1) & 3)) << 4));
    }
    if (pf) g2_stage(A, Bt, lds, m0, n0, wave, lane, kt + 2);

    __builtin_amdgcn_s_setprio(1);
#pragma unroll
    for (int mi = 0; mi < 8; ++mi)
#pragma unroll
      for (int ni = 0; ni < 4; ++ni)
        acc[mi][ni] = __builtin_amdgcn_mfma_f32_16x16x32_f16(
            af[mi], bf[ni], acc[mi][ni], 0, 0, 0);
    __builtin_amdgcn_s_setprio(0);

    if (pf) asm volatile("s_waitcnt vmcnt(4)" ::: "memory");
    else    asm volatile("s_waitcnt vmcnt(0)" ::: "memory");
    __builtin_amdgcn_s_barrier();
  }

  // inline bias: cb = sum_{k<15} beta2^k (clamped beta2)
  const float beta2 = fminf(fmaxf(beta2p[0], 0.1f), 0.9f);
  float cb = 0.0f;
  for (int i = 0; i < NSTEPS; ++i) cb = beta2 * cb + 1.0f;

  // ---- coalesced epilogue: per-wave LDS transpose, nt full-line stores ----
  float* wlds = (float*)(lds) + wave * 1040;   // 16 rows x 65 f32, stride-65 pad
  const int g  = lane >> 4;                    // 0..3 row group
  const int c  = lane & 15;                    // 0..15

#pragma unroll
  for (int mi = 0; mi < 8; ++mi) {
    __syncthreads();   // LDS region reuse fence (K-loop buffers / prev mi)
#pragma unroll
    for (int ni = 0; ni < 4; ++ni) {
      const int cc = n0 + wn * 64 + ni * 16 + c;
      const float bv = cb * b2[cc];
#pragma unroll
      for (int q = 0; q < 4; ++q)
        wlds[(g * 4 + q) * 65 + ni * 16 + c] = acc[mi][ni][q] + bv;
    }
    __syncthreads();   // within-wave lgkmcnt + uniform re-convergence
    const int r0 = m0 + wm * 128 + mi * 16;
#pragma unroll
    for (int it = 0; it < 4; ++it) {
      const int rr = it * 4 + g;              // 0..15
      f32x4 v;
#pragma unroll
      for (int jj = 0; jj < 4; ++jj) v[jj] = wlds[rr * 65 + c * 4 + jj];
      // non-temporal: C is write-once, never re-read
      __builtin_nontemporal_store(
          v, (f32x4*)&C[(size_t)(r0 + rr) * 2048 + n0 + wn * 64 + c * 4]);
    }
  }
}

// ---------------------------------------------------------------------------
extern "C" void kernel_launch(void* const* d_in, const int* in_sizes, int n_in,
                              void* d_out, int out_size, void* d_ws, size_t ws_size,
                              hipStream_t stream) {
  const int*   x     = (const int*)  d_in[0];
  const float* embed = (const float*)d_in[1];
  const float* W1    = (const float*)d_in[2];
  const float* b1    = (const float*)d_in[3];
  const float* W2    = (const float*)d_in[4];
  const float* b2    = (const float*)d_in[5];
  const float* beta1 = (const float*)d_in[6];
  const float* thr1  = (const float*)d_in[7];
  const float* beta2 = (const float*)d_in[8];
  // d_in[9] = thr2: clipped but unused by the output
  float* out = (float*)d_out;

  char* ws = (char*)d_ws;
  float*    T   = (float*)   ws;                   //  8 MB [2048][1024]
  _Float16* Ap  = (_Float16*)(ws + ( 8u << 20));   //  4 MB [2048][1024]
  _Float16* Btp = (_Float16*)(ws + (12u << 20));   //  2 MB [1024][1024]
  _Float16* W2T = (_Float16*)(ws + (14u << 20));   //  2 MB [2048][512]
  _Float16* S   = (_Float16*)(ws + (16u << 20));   //  8 MB [8192][512]

  prep_kernel<<<dim3(1408), 256, 0, stream>>>(embed, W1, W2, Ap, Btp, W2T);

  gemm1_kernel<<<dim3(512), 256, 0, stream>>>(Ap, Btp, T);

  recur_kernel<<<dim3(2048), 256, 0, stream>>>(x, T, b1, beta1, thr1, beta2, S);

  // out = S @ W2 + cb*b2  (256x256/BK32, 1 block/CU, issued reads 128MB)
  gemm2_pipe_kernel<<<dim3(256), 512, 0, stream>>>(S, W2T, b2, beta2, out);
}

// Round 18
// 60.760 us; speedup vs baseline: 1.0336x; 1.0336x over previous
//
#include <hip/hip_runtime.h>
#include <hip/hip_bf16.h>
#include <stdint.h>

typedef float    f32x4 __attribute__((ext_vector_type(4)));
typedef _Float16 f16x4 __attribute__((ext_vector_type(4)));
typedef _Float16 f16x8 __attribute__((ext_vector_type(8)));

#define NSTEPS 15

// ---------------------------------------------------------------------------
// Fused prep kernel (byte-identical to R13)
// ---------------------------------------------------------------------------
__global__ __launch_bounds__(256) void prep_kernel(
    const float* __restrict__ embed, const float* __restrict__ W1,
    const float* __restrict__ W2,
    _Float16* __restrict__ Ap, _Float16* __restrict__ Btp,
    _Float16* __restrict__ W2T)
{
  __shared__ _Float16 sh[2][64][72];
  const int b = blockIdx.x;
  const int t = threadIdx.x;

  if (b < 1024) {                       // ---- split_e (Dekker two-way split)
    const int i  = b * 256 + t;
    const int m  = i >> 7;
    const int k4 = (i & 127) * 4;
    f32x4 v = *(const f32x4*)&embed[(size_t)m * 512 + k4];
    f16x4 h0, h1;
#pragma unroll
    for (int j = 0; j < 4; ++j) {
      h0[j] = (_Float16)v[j];
      h1[j] = (_Float16)(v[j] - (float)h0[j]);
    }
    _Float16* r = Ap + (size_t)m * 1024 + k4;
    *(f16x4*)(r)       = h0;
    *(f16x4*)(r + 512) = h1;
  } else if (b < 1152) {                // ---- w1t_split (transpose + 64x + split)
    const int idx = b - 1024;
    const int n0 = (idx & 7) * 64;
    const int k0 = ((idx >> 3) & 7) * 64;
    const int z  = idx >> 6;
    const int kk = t >> 4;
    const int n4 = (t & 15) * 4;
#pragma unroll
    for (int i = 0; i < 4; ++i) {
      f32x4 v = *(const f32x4*)&W1[(size_t)(z * 512 + k0 + kk + i * 16) * 512 + n0 + n4];
#pragma unroll
      for (int j = 0; j < 4; ++j) {
        float s = v[j] * 64.0f;         // exact pow2 scale
        _Float16 hi = (_Float16)s;
        sh[0][n4 + j][kk + i * 16] = hi;
        sh[1][n4 + j][kk + i * 16] = (_Float16)(s - (float)hi);
      }
    }
    __syncthreads();
#pragma unroll
    for (int i = 0; i < 2; ++i) {
      const int nn = (t >> 3) + i * 32;
      const int k8 = (t & 7) * 8;
      _Float16* r = Btp + (size_t)(z * 512 + n0 + nn) * 1024 + k0 + k8;
      *(uint4*)(r)       = *(const uint4*)&sh[0][nn][k8];
      *(uint4*)(r + 512) = *(const uint4*)&sh[1][nn][k8];
    }
  } else {                              // ---- w2t (transpose + f16 convert)
    const int idx = b - 1152;
    const int n0 = (idx & 31) * 64;
    const int k0 = (idx >> 5) * 64;
    const int kk = t >> 4;
    const int n4 = (t & 15) * 4;
#pragma unroll
    for (int i = 0; i < 4; ++i) {
      f32x4 v = *(const f32x4*)&W2[(size_t)(k0 + kk + i * 16) * 2048 + n0 + n4];
#pragma unroll
      for (int j = 0; j < 4; ++j) sh[0][n4 + j][kk + i * 16] = (_Float16)v[j];
    }
    __syncthreads();
#pragma unroll
    for (int i = 0; i < 2; ++i) {
      const int nn = (t >> 3) + i * 32;
      const int k8 = (t & 7) * 8;
      *(uint4*)&W2T[(size_t)(n0 + nn) * 512 + k0 + k8] = *(const uint4*)&sh[0][nn][k8];
    }
  }
}

// ---------------------------------------------------------------------------
__device__ __forceinline__ void gld_lds16(const void* g, void* l) {
  __builtin_amdgcn_global_load_lds(
      (const __attribute__((address_space(1))) uint32_t*)g,
      (__attribute__((address_space(3))) uint32_t*)l, 16, 0, 0);
}

// ---------------------------------------------------------------------------
// gemm1 v3 (64x64 full-K, 4-DEEP ring): T = (1/64)*Ap@Btp^T, virtual K=1536
// Stage distance 3 (tile kt+3 during window kt); counted vmcnt(8) leaves the
// last two staged tiles in flight, tile kt+1 guaranteed resident. Tail uses
// exact drains 8/4/0. Accumulation order identical to R11 -> bitwise-same T.
// LDS 64 KB -> still 2 blocks/CU.
// ---------------------------------------------------------------------------
__device__ __forceinline__ void g1_stage(
    const _Float16* __restrict__ Ap, const _Float16* __restrict__ Btp,
    char* lds, int m0, int n0, int wave, int lane, int tile)
{
  const int vk0  = tile * 64;
  const int acol = (vk0 < 1024) ? vk0 : vk0 - 1024;
  const int bcol = (vk0 < 1024) ? (vk0 & 511) : vk0 - 512;
  char* lb = lds + (tile & 3) * 16384;
#pragma unroll
  for (int i = 0; i < 2; ++i) {      // A: 8 x 1KB chunks, 2 per wave
    const int ob  = (wave * 2 + i) * 1024;
    const int o   = ob + lane * 16;
    const int row = o >> 7;
    const int c   = ((o >> 4) & 7) ^ (row & 7);
    gld_lds16(Ap + ((size_t)(m0 + row) * 1024 + acol + c * 8), lb + ob);
  }
#pragma unroll
  for (int i = 0; i < 2; ++i) {      // B: 8 x 1KB chunks, 2 per wave
    const int ob  = (wave * 2 + i) * 1024;
    const int o   = ob + lane * 16;
    const int row = o >> 7;
    const int c   = ((o >> 4) & 7) ^ (row & 7);
    gld_lds16(Btp + ((size_t)(n0 + row) * 1024 + bcol + c * 8), lb + 8192 + ob);
  }
}

__global__ __launch_bounds__(256) void gemm1_kernel(
    const _Float16* __restrict__ Ap,   // [2048][1024]
    const _Float16* __restrict__ Btp,  // [1024][1024]
    float* __restrict__ T)             // [2048][1024]
{
  __shared__ __align__(16) char lds[4 * 16384];   // 64 KB ring

  const int t    = threadIdx.x;
  const int lane = t & 63;
  const int wave = t >> 6;
  const int wm   = wave >> 1;
  const int wn   = wave & 1;

  int bid = blockIdx.x;
  bid = (bid & 7) * 64 + (bid >> 3);   // XCD swizzle (512 % 8 == 0)
  const int m0 = (bid >> 4) * 64;      // 32 m-tiles
  const int n0 = (bid & 15) * 64;      // 16 n-tiles

  f32x4 acc[2][2] = {};

  // prologue: stage tiles 0,1,2; vmcnt(8) -> tile 0 resident
  g1_stage(Ap, Btp, lds, m0, n0, wave, lane, 0);
  g1_stage(Ap, Btp, lds, m0, n0, wave, lane, 1);
  g1_stage(Ap, Btp, lds, m0, n0, wave, lane, 2);
  asm volatile("s_waitcnt vmcnt(8)" ::: "memory");
  __builtin_amdgcn_s_barrier();

  for (int kt = 0; kt < 24; ++kt) {
    const char* lb = lds + (kt & 3) * 16384;
    char* AsB = (char*)lb;
    char* BsB = (char*)lb + 8192;

    f16x8 af[2][2], bf[2][2];
#pragma unroll
    for (int kk = 0; kk < 2; ++kk) {
      const int lc = (lane >> 4) + kk * 4;
#pragma unroll
      for (int mi = 0; mi < 2; ++mi) {
        const int row = wm * 32 + mi * 16 + (lane & 15);
        af[mi][kk] = *(const f16x8*)(AsB + row * 128 + ((lc ^ (row & 7)) << 4));
      }
#pragma unroll
      for (int ni = 0; ni < 2; ++ni) {
        const int row = wn * 32 + ni * 16 + (lane & 15);
        bf[ni][kk] = *(const f16x8*)(BsB + row * 128 + ((lc ^ (row & 7)) << 4));
      }
    }
    if (kt + 3 < 24) g1_stage(Ap, Btp, lds, m0, n0, wave, lane, kt + 3);

    __builtin_amdgcn_s_setprio(1);
#pragma unroll
    for (int kk = 0; kk < 2; ++kk)
#pragma unroll
      for (int mi = 0; mi < 2; ++mi)
#pragma unroll
        for (int ni = 0; ni < 2; ++ni)
          acc[mi][ni] = __builtin_amdgcn_mfma_f32_16x16x32_f16(
              af[mi][kk], bf[ni][kk], acc[mi][ni], 0, 0, 0);
    __builtin_amdgcn_s_setprio(0);

    // counted drain: tile kt+1 complete; later staged tiles stay in flight.
    // staged_max = min(kt+3, 23); allowed = 4*(staged_max - (kt+1)).
    if (kt <= 20)      asm volatile("s_waitcnt vmcnt(8)" ::: "memory");
    else if (kt == 21) asm volatile("s_waitcnt vmcnt(4)" ::: "memory");
    else if (kt == 22) asm volatile("s_waitcnt vmcnt(0)" ::: "memory");
    __builtin_amdgcn_s_barrier();
  }

  // epilogue: C/D layout col=lane&15, row=(lane>>4)*4+reg
#pragma unroll
  for (int mi = 0; mi < 2; ++mi) {
    const int r0 = m0 + wm * 32 + mi * 16 + ((lane >> 4) << 2);
#pragma unroll
    for (int ni = 0; ni < 2; ++ni) {
      const int cc = n0 + wn * 32 + ni * 16 + (lane & 15);
#pragma unroll
      for (int q = 0; q < 4; ++q)
        T[(size_t)(r0 + q) * 1024 + cc] = acc[mi][ni][q] * 0.015625f;
    }
  }
}

// ---------------------------------------------------------------------------
// recur (byte-identical to R13)
// ---------------------------------------------------------------------------
__global__ __launch_bounds__(256) void recur_kernel(
    const int* __restrict__ x,        // [8192][2]
    const float* __restrict__ T,      // [2048][1024]
    const float* __restrict__ b1,     // [512]
    const float* __restrict__ beta1p, const float* __restrict__ thr1p,
    const float* __restrict__ beta2p,
    _Float16* __restrict__ S)         // [8192][512]
{
  const float beta1 = fminf(fmaxf(beta1p[0], 0.1f), 0.9f);
  const float thr1  = fmaxf(thr1p[0], 0.1f);
  const float beta2 = fminf(fmaxf(beta2p[0], 0.1f), 0.9f);

  const int t = threadIdx.x;
  const int b = blockIdx.x * 4 + (t >> 6);
  const int h = (t & 63) * 8;
  const int x0 = x[b * 2 + 0];
  const int x1 = x[b * 2 + 1];

  const float* p0 = &T[(size_t)x0 * 1024 + h];
  const float* p1 = &T[(size_t)x1 * 1024 + 512 + h];

  float cur[8];
#pragma unroll
  for (int half = 0; half < 2; ++half) {
    f32x4 a = *(const f32x4*)(p0 + half * 4);
    f32x4 c = *(const f32x4*)(p1 + half * 4);
    f32x4 e = *(const f32x4*)&b1[h + half * 4];
#pragma unroll
    for (int j = 0; j < 4; ++j)
      cur[half * 4 + j] = (a[j] + c[j]) + e[j];
  }

  float m[8] = {}, s[8] = {};
#pragma unroll
  for (int st = 0; st < NSTEPS; ++st) {
#pragma unroll
    for (int j = 0; j < 8; ++j) {
      // reset uses PREVIOUS mem; spike uses UPDATED mem (snntorch Leaky, subtract)
      float r = (m[j] > thr1) ? thr1 : 0.0f;
      m[j] = beta1 * m[j] + cur[j] - r;
      float sp = (m[j] > thr1) ? 1.0f : 0.0f;
      s[j] = beta2 * s[j] + sp;   // S = sum_t beta2^{15-t} spk_t
    }
  }

  __align__(16) _Float16 o[8];
#pragma unroll
  for (int j = 0; j < 8; ++j) o[j] = (_Float16)s[j];
  *(uint4*)&S[(size_t)b * 512 + h] = *(const uint4*)o;
}

// ---------------------------------------------------------------------------
// gemm2 (R15-exact, tied-best): 256x128 tile, BK=32, 3-deep ring, 2 blocks/CU,
// counted vmcnt(3), coalesced LDS-transpose epilogue + nt full-line stores.
// ---------------------------------------------------------------------------
__device__ __forceinline__ void g2_stage(
    const _Float16* __restrict__ A, const _Float16* __restrict__ Bt,
    char* lds, int m0, int n0, int wave, int lane, int tile)
{
  const int k0 = tile * 32;
  char* lb = lds + (tile % 3) * 24576;
#pragma unroll
  for (int i = 0; i < 2; ++i) {      // A: 256 rows x 64B = 16 chunks, 2/wave
    const int ob  = i * 8192 + wave * 1024;
    const int o   = ob + lane * 16;
    const int row = o >> 6;
    const int c   = ((o >> 4) & 3) ^ ((row >> 1) & 3);
    gld_lds16(A + ((size_t)(m0 + row) * 512 + k0 + c * 8), lb + ob);
  }
  {                                  // B: 128 rows x 64B = 8 chunks, 1/wave
    const int ob  = wave * 1024;
    const int o   = ob + lane * 16;
    const int row = o >> 6;
    const int c   = ((o >> 4) & 3) ^ ((row >> 1) & 3);
    gld_lds16(Bt + ((size_t)(n0 + row) * 512 + k0 + c * 8), lb + 16384 + ob);
  }
}

__global__ __launch_bounds__(512, 4) void gemm2_pipe_kernel(
    const _Float16* __restrict__ A,    // S   [8192][512]
    const _Float16* __restrict__ Bt,   // W2T [2048][512]
    const float* __restrict__ b2,      // [2048]
    const float* __restrict__ beta2p,
    float* __restrict__ C)             // [8192][2048]
{
  __shared__ __align__(16) char lds[3 * 24576];   // 72 KB

  const int t    = threadIdx.x;
  const int lane = t & 63;
  const int wave = t >> 6;
  const int wm   = wave >> 1;   // 0..3
  const int wn   = wave & 1;    // 0..1

  // L2-locality swizzle: XCD = bid&7 owns m-groups [4*xcd, 4*xcd+4)
  const int bid = blockIdx.x;          // 0..511
  const int xcd = bid & 7;
  const int j   = bid >> 3;            // 0..63
  const int m0  = (xcd * 4 + (j >> 4)) * 256;   // 32 m-groups
  const int n0  = (j & 15) * 128;               // 16 n-groups

  f32x4 acc[4][4] = {};

  g2_stage(A, Bt, lds, m0, n0, wave, lane, 0);
  g2_stage(A, Bt, lds, m0, n0, wave, lane, 1);
  asm volatile("s_waitcnt vmcnt(3)" ::: "memory");
  __builtin_amdgcn_s_barrier();

  for (int kt = 0; kt < 16; ++kt) {
    const char* lb = lds + (kt % 3) * 24576;
    const bool pf = (kt + 2 < 16);

    const int lc = lane >> 4;
    f16x8 af[4], bf[4];
#pragma unroll
    for (int mi = 0; mi < 4; ++mi) {
      const int row = wm * 64 + mi * 16 + (lane & 15);
      af[mi] = *(const f16x8*)(lb + row * 64 + ((lc ^ ((row >> 1) & 3)) << 4));
    }
#pragma unroll
    for (int ni = 0; ni < 4; ++ni) {
      const int row = wn * 64 + ni * 16 + (lane & 15);
      bf[ni] = *(const f16x8*)(lb + 16384 + row * 64 + ((lc ^ ((row >> 1) & 3)) << 4));
    }
    if (pf) g2_stage(A, Bt, lds, m0, n0, wave, lane, kt + 2);

    __builtin_amdgcn_s_setprio(1);
#pragma unroll
    for (int mi = 0; mi < 4; ++mi)
#pragma unroll
      for (int ni = 0; ni < 4; ++ni)
        acc[mi][ni] = __builtin_amdgcn_mfma_f32_16x16x32_f16(
            af[mi], bf[ni], acc[mi][ni], 0, 0, 0);
    __builtin_amdgcn_s_setprio(0);

    if (pf) asm volatile("s_waitcnt vmcnt(3)" ::: "memory");
    else    asm volatile("s_waitcnt vmcnt(0)" ::: "memory");
    __builtin_amdgcn_s_barrier();
  }

  // inline bias: cb = sum_{k<15} beta2^k (clamped beta2)
  const float beta2 = fminf(fmaxf(beta2p[0], 0.1f), 0.9f);
  float cb = 0.0f;
  for (int i = 0; i < NSTEPS; ++i) cb = beta2 * cb + 1.0f;

  // ---- coalesced epilogue: per-wave LDS transpose, nt full-line stores ----
  float* wlds = (float*)(lds) + wave * 1040;   // 16 rows x 65 f32, stride-65 pad
  const int g  = lane >> 4;                    // 0..3 row group
  const int c  = lane & 15;                    // 0..15

#pragma unroll
  for (int mi = 0; mi < 4; ++mi) {
    __syncthreads();   // LDS region reuse fence (K-loop buffers / prev mi)
#pragma unroll
    for (int ni = 0; ni < 4; ++ni) {
      const int cc = n0 + wn * 64 + ni * 16 + c;
      const float bv = cb * b2[cc];
#pragma unroll
      for (int q = 0; q < 4; ++q)
        wlds[(g * 4 + q) * 65 + ni * 16 + c] = acc[mi][ni][q] + bv;
    }
    __syncthreads();   // within-wave lgkmcnt + uniform re-convergence
    const int r0 = m0 + wm * 64 + mi * 16;
#pragma unroll
    for (int it = 0; it < 4; ++it) {
      const int rr = it * 4 + g;              // 0..15
      f32x4 v;
#pragma unroll
      for (int jj = 0; jj < 4; ++jj) v[jj] = wlds[rr * 65 + c * 4 + jj];
      // non-temporal: C is write-once, never re-read
      __builtin_nontemporal_store(
          v, (f32x4*)&C[(size_t)(r0 + rr) * 2048 + n0 + wn * 64 + c * 4]);
    }
  }
}

// ---------------------------------------------------------------------------
extern "C" void kernel_launch(void* const* d_in, const int* in_sizes, int n_in,
                              void* d_out, int out_size, void* d_ws, size_t ws_size,
                              hipStream_t stream) {
  const int*   x     = (const int*)  d_in[0];
  const float* embed = (const float*)d_in[1];
  const float* W1    = (const float*)d_in[2];
  const float* b1    = (const float*)d_in[3];
  const float* W2    = (const float*)d_in[4];
  const float* b2    = (const float*)d_in[5];
  const float* beta1 = (const float*)d_in[6];
  const float* thr1  = (const float*)d_in[7];
  const float* beta2 = (const float*)d_in[8];
  // d_in[9] = thr2: clipped but unused by the output
  float* out = (float*)d_out;

  char* ws = (char*)d_ws;
  float*    T   = (float*)   ws;                   //  8 MB [2048][1024]
  _Float16* Ap  = (_Float16*)(ws + ( 8u << 20));   //  4 MB [2048][1024]
  _Float16* Btp = (_Float16*)(ws + (12u << 20));   //  2 MB [1024][1024]
  _Float16* W2T = (_Float16*)(ws + (14u << 20));   //  2 MB [2048][512]
  _Float16* S   = (_Float16*)(ws + (16u << 20));   //  8 MB [8192][512]

  prep_kernel<<<dim3(1408), 256, 0, stream>>>(embed, W1, W2, Ap, Btp, W2T);

  // T = embed@W1 pre-summed (64x64 tile, K=1536, 4-deep ring, vmcnt(8))
  gemm1_kernel<<<dim3(512), 256, 0, stream>>>(Ap, Btp, T);

  recur_kernel<<<dim3(2048), 256, 0, stream>>>(x, T, b1, beta1, thr1, beta2, S);

  // out = S @ W2 + cb*b2  (R15-exact gemm2: 256x128/BK32, 2 blocks/CU)
  gemm2_pipe_kernel<<<dim3(512), 512, 0, stream>>>(S, W2T, b2, beta2, out);
}